// Round 16
// baseline (1510.848 us; speedup 1.0000x reference)
//
#include <hip/hip_runtime.h>
#include <hip/hip_bf16.h>
#include <stdint.h>

// Problem constants (all static per reference)
#define TOK   16384
#define DIMM  512
#define NHEAD 16
#define HDIM  32
#define HID   2048
#define NWIN  256
#define WLEN  64
#define EPSV  1e-5f
#define SCL   0.17677669529663687f   // 32^-0.5

typedef __hip_bfloat16 bf16;
typedef __attribute__((ext_vector_type(8))) __bf16 bf16x8;
typedef __attribute__((ext_vector_type(4))) float f32x4;

// window-order row r (win*64 + l, shifted coords) -> original token row
__device__ __forceinline__ int remap_row(int r){
  int win = r >> 6, l = r & 63;
  int gh = ((win >> 4) << 3) + (l >> 3);
  int gw = ((win & 15) << 3) + (l & 7);
  int oh = (gh + 4) & 127, ow = (gw + 4) & 127;
  return (oh << 7) + ow;
}

// Swin shift-mask region id (slices: [0,120) [120,124) [124,128) on each axis)
__device__ __forceinline__ int region_of(int win, int l){
  int gh = ((win >> 4) << 3) + (l >> 3);
  int gw = ((win & 15) << 3) + (l & 7);
  int rh = (gh < 120) ? 0 : ((gh < 124) ? 1 : 2);
  int rw = (gw < 120) ? 0 : ((gw < 124) ? 1 : 2);
  return rh * 3 + rw;
}

__device__ __forceinline__ void gl_lds16(const bf16* g, bf16* l){
  __builtin_amdgcn_global_load_lds((const __attribute__((address_space(1))) void*)g,
                                   (__attribute__((address_space(3))) void*)l, 16, 0, 0);
}

// ---------------- weight fp32 -> bf16 convert (4 ranges, contiguous dst) -------------
__global__ __launch_bounds__(256) void convert_w(const float* __restrict__ a,
                                                 const float* __restrict__ b,
                                                 const float* __restrict__ c,
                                                 const float* __restrict__ d,
                                                 bf16* __restrict__ dst){
  int e = (blockIdx.x * 256 + threadIdx.x) * 4;
  float4 v;
  if (e < 786432)        v = *(const float4*)(a + e);
  else if (e < 1048576)  v = *(const float4*)(b + (e - 786432));
  else if (e < 2097152)  v = *(const float4*)(c + (e - 1048576));
  else                   v = *(const float4*)(d + (e - 2097152));
  union { bf16 h[4]; int2 q; } u;
  u.h[0] = __float2bfloat16(v.x); u.h[1] = __float2bfloat16(v.y);
  u.h[2] = __float2bfloat16(v.z); u.h[3] = __float2bfloat16(v.w);
  *(int2*)(dst + e) = u.q;
}

// ---------------- LayerNorm (one wave per row) + shift+window remap (LN1 only) -------
template<bool REMAP>
__global__ __launch_bounds__(256) void ln_kernel(const float* __restrict__ in,
    const float* __restrict__ w, const float* __restrict__ b, bf16* __restrict__ outp)
{
  const int wave = threadIdx.x >> 6, lane = threadIdx.x & 63;
  const int r = blockIdx.x * 4 + wave;
  const int src = REMAP ? remap_row(r) : r;
  const float4* row = (const float4*)(in + (size_t)src * DIMM);
  float4 v0 = row[lane*2], v1 = row[lane*2 + 1];
  float sm = v0.x+v0.y+v0.z+v0.w + v1.x+v1.y+v1.z+v1.w;
  float sq = v0.x*v0.x+v0.y*v0.y+v0.z*v0.z+v0.w*v0.w
           + v1.x*v1.x+v1.y*v1.y+v1.z*v1.z+v1.w*v1.w;
  #pragma unroll
  for (int off = 1; off < 64; off <<= 1){
    sm += __shfl_xor(sm, off);
    sq += __shfl_xor(sq, off);
  }
  const float mean = sm * (1.f/512.f);
  const float rstd = rsqrtf(sq*(1.f/512.f) - mean*mean + EPSV);
  const float4* wp = (const float4*)w; const float4* bp = (const float4*)b;
  float4 w0 = wp[lane*2], w1 = wp[lane*2+1], b0 = bp[lane*2], b1 = bp[lane*2+1];
  union { bf16 h[8]; int4 q; } u;
  u.h[0] = __float2bfloat16((v0.x-mean)*rstd*w0.x + b0.x);
  u.h[1] = __float2bfloat16((v0.y-mean)*rstd*w0.y + b0.y);
  u.h[2] = __float2bfloat16((v0.z-mean)*rstd*w0.z + b0.z);
  u.h[3] = __float2bfloat16((v0.w-mean)*rstd*w0.w + b0.w);
  u.h[4] = __float2bfloat16((v1.x-mean)*rstd*w1.x + b1.x);
  u.h[5] = __float2bfloat16((v1.y-mean)*rstd*w1.y + b1.y);
  u.h[6] = __float2bfloat16((v1.z-mean)*rstd*w1.z + b1.z);
  u.h[7] = __float2bfloat16((v1.w-mean)*rstd*w1.w + b1.w);
  *(int4*)(outp + (size_t)r*DIMM + lane*8) = u.q;
}

#define M_QKV  0
#define M_MLP1 2
#define M_PART 4

// ---------------- 256x256 GEMM, single-buffer LDS, 2 blocks/CU (R15->R16) ------------
// Occupancy matrix completion: R10 failed at 1 wave/SIMD (no TLP), R14 failed
// with 4-wave blocks + BK=32 (doubled barrier frequency). Untested cell:
// 8-wave block + BK=64 + 2 blocks/CU. Enabler: SINGLE-buffered LDS (64 KB vs
// gemm8's 128 KB dbuf) -> 2 blocks fit; __launch_bounds__(512,4) = 4 waves/SIMD
// = 16 waves/CU (VGPR cap 128 = R13's exact measured usage). Same geometry as
// gemm8 (128x64 wave tile, 42.7 FLOP/LDS-B, same swizzle/frag/epilogue).
// Loop is the trivially-race-free m97-style: STAGE(t) -> __syncthreads (drains
// vmcnt: staged data visible) -> 24 ds_reads + 64 MFMA (compiler inserts
// fine-grained lgkm) -> __syncthreads (reads retired before next overwrite).
// Staging latency is fully exposed PER BLOCK and covered by the co-resident
// block's MFMA phase (m114 cross-block overlap - m97's 874 TF mechanism).
template<int KSTR>
__device__ __forceinline__ void stage_ht(const bf16* __restrict__ P,
                                         int grow0, bf16* lbase, int tid, int kt){
  const int r = tid >> 3;
  const int c = ((tid & 7) ^ (r & 7)) * 8;      // pre-swizzled source column
  const bf16* g = P + (size_t)(grow0 + r) * KSTR + kt * 64 + c;
  bf16* l = lbase + r * 64 + (tid & 7) * 8;     // linear dest (wave base + lane*16B)
  gl_lds16(g, l);
  gl_lds16(g + (size_t)64 * KSTR, l + 4096);
}

template<int MODE, int KEXT, int KSTR = KEXT>
__global__ __launch_bounds__(512, 4) void gemm_sb(const bf16* __restrict__ A,
    const bf16* __restrict__ Wt, const float* __restrict__ bias,
    bf16* __restrict__ out_b, float* __restrict__ out_f, float* __restrict__ out_f2)
{
  constexpr int NT = KEXT / 64;
  extern __shared__ bf16 lds[];
  bf16* As = lds;            // [256][64] swizzled (32 KB)
  bf16* Bs = lds + 16384;    // [256][64] swizzled (32 KB)
  const int tid = threadIdx.x;
  const int ln = tid & 63, wv = tid >> 6;
  const int lrow = ln & 15, lgrp = ln >> 4;
  const int swz = lrow & 7;
  const int wm = wv >> 2, wn = wv & 3;
  const int m0 = blockIdx.x * 256, n0 = blockIdx.y * 256;

  if constexpr (MODE == M_PART){          // split-K slab select
    A  += blockIdx.z * 1024;
    Wt += blockIdx.z * 1024;
  }

  f32x4 acc[8][4] = {};
  bf16x8 aA0[4][2], aA1[4][2], bB0[2][2], bB1[2][2];

  #define LDAS(DST, MH) { _Pragma("unroll") for (int mf = 0; mf < 4; mf++) \
    _Pragma("unroll") for (int ks = 0; ks < 2; ks++) \
      DST[mf][ks] = *(const bf16x8*)(As + (wm*128 + (MH)*64 + mf*16 + lrow)*64 + ((ks*4 + lgrp) ^ swz)*8); }
  #define LDBS(DST, NH) { _Pragma("unroll") for (int nf = 0; nf < 2; nf++) \
    _Pragma("unroll") for (int ks = 0; ks < 2; ks++) \
      DST[nf][ks] = *(const bf16x8*)(Bs + (wn*64 + (NH)*32 + nf*16 + lrow)*64 + ((ks*4 + lgrp) ^ swz)*8); }
  #define QUAD(AR, BR, IM0, JN0) { _Pragma("unroll") for (int ks = 0; ks < 2; ks++) \
    _Pragma("unroll") for (int mf = 0; mf < 4; mf++) \
      _Pragma("unroll") for (int nf = 0; nf < 2; nf++) \
        acc[(IM0)+mf][(JN0)+nf] = __builtin_amdgcn_mfma_f32_16x16x32_bf16(AR[mf][ks], BR[nf][ks], acc[(IM0)+mf][(JN0)+nf], 0, 0, 0); }

  for (int t = 0; t < NT; ++t){
    stage_ht<KSTR>(A,  m0,       As,        tid, t);
    stage_ht<KSTR>(A,  m0 + 128, As + 8192, tid, t);
    stage_ht<KSTR>(Wt, n0,       Bs,        tid, t);
    stage_ht<KSTR>(Wt, n0 + 128, Bs + 8192, tid, t);
    __syncthreads();   // compiler drains vmcnt(0): staged K(t) visible
    LDAS(aA0, 0); LDAS(aA1, 1); LDBS(bB0, 0); LDBS(bB1, 1);
    __builtin_amdgcn_s_setprio(1);
    QUAD(aA0, bB0, 0, 0);
    QUAD(aA1, bB0, 4, 0);
    QUAD(aA0, bB1, 0, 2);
    QUAD(aA1, bB1, 4, 2);
    __builtin_amdgcn_s_setprio(0);
    __syncthreads();   // reads retired before K(t+1) overwrites the buffer
  }
  #undef LDAS
  #undef LDBS
  #undef QUAD

  // ---- epilogue (identical to gemm8)
  bf16* pdstb = nullptr;
  if constexpr (MODE == M_PART)
    pdstb = blockIdx.z ? (bf16*)out_f2 : (bf16*)out_f;   // bf16 split-K partials
  #pragma unroll
  for (int im = 0; im < 8; im++){
    #pragma unroll
    for (int jn = 0; jn < 4; jn++){
      const int col = n0 + wn*64 + (jn >> 1)*32 + (jn & 1)*16 + lrow;
      const int row_b = m0 + wm*128 + (im >> 2)*64 + (im & 3)*16 + lgrp*4;
      const float bv = (MODE == M_PART) ? 0.f : bias[col];
      #pragma unroll
      for (int rr = 0; rr < 4; rr++){
        const int row = row_b + rr;
        float v = acc[im][jn][rr] + bv;
        if constexpr (MODE == M_QKV){
          const int t = col >> 9, rem = col & 511;
          const int head = rem >> 5, hd = rem & 31;
          const int win = row >> 6, l = row & 63;
          out_b[(size_t)t * (TOK*DIMM) + ((size_t)(win*NHEAD + head)*WLEN + l)*HDIM + hd]
              = __float2bfloat16(v);
        } else if constexpr (MODE == M_MLP1){
          const float u = 1.5957691216057308f * (v + 0.044715f*v*v*v);
          const float g = v * (1.0f / (1.0f + __expf(-u)));
          out_b[(size_t)row*HID + col] = __float2bfloat16(g);
        } else if constexpr (MODE == M_PART){
          pdstb[(size_t)row*DIMM + col] = __float2bfloat16(v);  // raw partial
        }
      }
    }
  }
}

// -------- fused PROJ + residual + LayerNorm2: h never materialized (R12, proven) -----
__global__ __launch_bounds__(512, 1) void gemm_pl(const bf16* __restrict__ Ain,
    const bf16* __restrict__ Wt, const float* __restrict__ pb,
    const float* __restrict__ x, const float* __restrict__ w2,
    const float* __restrict__ b2, bf16* __restrict__ h2)
{
  extern __shared__ bf16 lds[];
  bf16* As = lds;            // [2][64][32]  = 8 KB
  bf16* Bs = lds + 4096;     // [2][512][32] = 64 KB
  const int tid = threadIdx.x;
  const int ln = tid & 63, wv = tid >> 6;
  const int lrow = ln & 15, lgrp = ln >> 4;
  const int m0 = blockIdx.x * 64;

  f32x4 acc[4][4] = {};

  const int brow = tid >> 2;                                // 0..127
  const int bchunk = ((tid & 3) ^ ((tid >> 3) & 3)) * 8;    // swizzled src col
  const int dst = brow * 32 + (tid & 3) * 8;                // linear dest

  #define STAGE(kt, sl) { \
    _Pragma("unroll") for (int i = 0; i < 4; i++) \
      gl_lds16(Wt + (size_t)(i*128 + brow)*DIMM + (kt)*32 + bchunk, Bs + (sl)*16384 + i*4096 + dst); \
    if (tid < 256) gl_lds16(Ain + (size_t)(m0 + brow)*DIMM + (kt)*32 + bchunk, As + (sl)*2048 + dst); \
  }

  const int rswz = (lgrp ^ ((lrow >> 1) & 3)) * 8;

  STAGE(0, 0);
  __syncthreads();
  for (int kt = 0; kt < 16; ++kt){
    const int s = kt & 1;
    if (kt + 1 < 16) STAGE(kt + 1, s ^ 1);
    bf16x8 a[4], b[4];
    #pragma unroll
    for (int mf = 0; mf < 4; mf++)
      a[mf] = *(const bf16x8*)(As + s*2048 + (mf*16 + lrow)*32 + rswz);
    #pragma unroll
    for (int nf = 0; nf < 4; nf++)
      b[nf] = *(const bf16x8*)(Bs + s*16384 + (wv*64 + nf*16 + lrow)*32 + rswz);
    #pragma unroll
    for (int mf = 0; mf < 4; mf++)
      #pragma unroll
      for (int nf = 0; nf < 4; nf++)
        acc[mf][nf] = __builtin_amdgcn_mfma_f32_16x16x32_bf16(a[mf], b[nf], acc[mf][nf], 0, 0, 0);
    __syncthreads();
  }
  #undef STAGE

  // ---- epilogue: residual + row stats (As/Bs dead past final barrier)
  float* red = (float*)lds;   // [8][64][2] f32 = 4 KB
  #pragma unroll
  for (int mf = 0; mf < 4; mf++){
    #pragma unroll
    for (int rr = 0; rr < 4; rr++){
      const int r = mf*16 + lgrp*4 + rr;
      const int o = remap_row(m0 + r);
      float sm = 0.f, sq = 0.f;
      #pragma unroll
      for (int nf = 0; nf < 4; nf++){
        const int col = wv*64 + nf*16 + lrow;
        float v = acc[mf][nf][rr] + pb[col] + x[(size_t)o*DIMM + col];
        acc[mf][nf][rr] = v;
        sm += v; sq += v*v;
      }
      sm += __shfl_xor(sm, 1); sq += __shfl_xor(sq, 1);
      sm += __shfl_xor(sm, 2); sq += __shfl_xor(sq, 2);
      sm += __shfl_xor(sm, 4); sq += __shfl_xor(sq, 4);
      sm += __shfl_xor(sm, 8); sq += __shfl_xor(sq, 8);
      if (lrow == 0){ red[(wv*64 + r)*2] = sm; red[(wv*64 + r)*2 + 1] = sq; }
    }
  }
  __syncthreads();
  if (tid < 64){
    float sm = 0.f, sq = 0.f;
    #pragma unroll
    for (int w = 0; w < 8; w++){ sm += red[(w*64 + tid)*2]; sq += red[(w*64 + tid)*2 + 1]; }
    const float mean = sm * (1.f/512.f);
    const float var  = sq * (1.f/512.f) - mean*mean;
    red[tid*2]     = mean;
    red[tid*2 + 1] = rsqrtf(var + EPSV);
  }
  __syncthreads();
  #pragma unroll
  for (int mf = 0; mf < 4; mf++){
    #pragma unroll
    for (int rr = 0; rr < 4; rr++){
      const int r = mf*16 + lgrp*4 + rr;
      const int o = remap_row(m0 + r);
      const float mean = red[r*2], rstd = red[r*2 + 1];
      #pragma unroll
      for (int nf = 0; nf < 4; nf++){
        const int col = wv*64 + nf*16 + lrow;
        const float g = (acc[mf][nf][rr] - mean) * rstd * w2[col] + b2[col];
        h2[(size_t)o*DIMM + col] = __float2bfloat16(g);
      }
    }
  }
}

// ---------------- MLP2 split-K reduce: d_out = 2*(p0 + p1 + bias), 8 elems/thread ----
__global__ __launch_bounds__(256) void mlp2_reduce(const bf16* __restrict__ p0,
    const bf16* __restrict__ p1, float* __restrict__ dout, const float* __restrict__ bias){
  const size_t i = (size_t)(blockIdx.x * 256 + threadIdx.x) * 8;
  int4 a = *(const int4*)(p0 + i);
  int4 b = *(const int4*)(p1 + i);
  const int cb = (int)(i & 511);
  const float4 bv0 = *(const float4*)(bias + cb);
  const float4 bv1 = *(const float4*)(bias + cb + 4);
  const bf16* ah = (const bf16*)&a;
  const bf16* bh = (const bf16*)&b;
  float4 r0, r1;
  r0.x = 2.f*(__bfloat162float(ah[0]) + __bfloat162float(bh[0]) + bv0.x);
  r0.y = 2.f*(__bfloat162float(ah[1]) + __bfloat162float(bh[1]) + bv0.y);
  r0.z = 2.f*(__bfloat162float(ah[2]) + __bfloat162float(bh[2]) + bv0.z);
  r0.w = 2.f*(__bfloat162float(ah[3]) + __bfloat162float(bh[3]) + bv0.w);
  r1.x = 2.f*(__bfloat162float(ah[4]) + __bfloat162float(bh[4]) + bv1.x);
  r1.y = 2.f*(__bfloat162float(ah[5]) + __bfloat162float(bh[5]) + bv1.y);
  r1.z = 2.f*(__bfloat162float(ah[6]) + __bfloat162float(bh[6]) + bv1.z);
  r1.w = 2.f*(__bfloat162float(ah[7]) + __bfloat162float(bh[7]) + bv1.w);
  *(float4*)(dout + i)     = r0;
  *(float4*)(dout + i + 4) = r1;
}

// ---------------- windowed attention: one wave per (window, head) --------------------
__global__ __launch_bounds__(256) void attn_kernel(const bf16* __restrict__ qkv,
    const float* __restrict__ rpb, bf16* __restrict__ outp)
{
  __shared__ bf16 Pl[4][64][72];
  const int wave = threadIdx.x >> 6, lane = threadIdx.x & 63;
  const int lrow = lane & 15, lgrp = lane >> 4;
  const int wh = blockIdx.x * 4 + wave;
  const int win = wh >> 4, head = wh & 15;
  const bf16* qb = qkv + (size_t)wh * (WLEN*HDIM);
  const bf16* kb = qb + (size_t)TOK * DIMM;
  const bf16* vb = kb + (size_t)TOK * DIMM;

  bf16x8 aq[4], ak[4];
  #pragma unroll
  for (int i = 0; i < 4; i++){
    aq[i] = *(const bf16x8*)(qb + (i*16 + lrow)*HDIM + lgrp*8);
    ak[i] = *(const bf16x8*)(kb + (i*16 + lrow)*HDIM + lgrp*8);
  }
  f32x4 s[4][4] = {};
  #pragma unroll
  for (int i = 0; i < 4; i++)
    #pragma unroll
    for (int j = 0; j < 4; j++)
      s[i][j] = __builtin_amdgcn_mfma_f32_16x16x32_bf16(aq[i], ak[j], s[i][j], 0, 0, 0);

  #pragma unroll
  for (int i = 0; i < 4; i++){
    #pragma unroll
    for (int rr = 0; rr < 4; rr++){
      const int srow = i*16 + lgrp*4 + rr;
      const int rq = region_of(win, srow);
      float vals[4]; float mx = -1e30f;
      #pragma unroll
      for (int j = 0; j < 4; j++){
        const int scol = j*16 + lrow;
        const int idx = ((srow>>3) - (scol>>3) + 7)*15 + ((srow&7) - (scol&7) + 7);
        float v = s[i][j][rr]*SCL + rpb[idx*NHEAD + head];
        if (region_of(win, scol) != rq) v -= 100.f;
        vals[j] = v; mx = fmaxf(mx, v);
      }
      mx = fmaxf(mx, __shfl_xor(mx, 1));
      mx = fmaxf(mx, __shfl_xor(mx, 2));
      mx = fmaxf(mx, __shfl_xor(mx, 4));
      mx = fmaxf(mx, __shfl_xor(mx, 8));
      float sum = 0.f;
      #pragma unroll
      for (int j = 0; j < 4; j++){ vals[j] = __expf(vals[j] - mx); sum += vals[j]; }
      sum += __shfl_xor(sum, 1); sum += __shfl_xor(sum, 2);
      sum += __shfl_xor(sum, 4); sum += __shfl_xor(sum, 8);
      const float rs = 1.f / sum;
      #pragma unroll
      for (int j = 0; j < 4; j++)
        Pl[wave][srow][j*16 + lrow] = __float2bfloat16(vals[j] * rs);
    }
  }

  f32x4 o[4][2] = {};
  const __bf16* vraw = (const __bf16*)vb;
  #pragma unroll
  for (int st = 0; st < 2; st++){
    bf16x8 pa[4];
    #pragma unroll
    for (int i = 0; i < 4; i++)
      pa[i] = *(const bf16x8*)(&Pl[wave][i*16 + lrow][st*32 + lgrp*8]);
    bf16x8 bv[2];
    #pragma unroll
    for (int j = 0; j < 2; j++){
      #pragma unroll
      for (int jj = 0; jj < 8; jj++)
        bv[j][jj] = vraw[(size_t)(st*32 + lgrp*8 + jj)*HDIM + j*16 + lrow];
    }
    #pragma unroll
    for (int i = 0; i < 4; i++)
      #pragma unroll
      for (int j = 0; j < 2; j++)
        o[i][j] = __builtin_amdgcn_mfma_f32_16x16x32_bf16(pa[i], bv[j], o[i][j], 0, 0, 0);
  }
  bf16* orow = outp + (size_t)win * WLEN * DIMM + head * HDIM;
  #pragma unroll
  for (int i = 0; i < 4; i++)
    #pragma unroll
    for (int j = 0; j < 2; j++)
      #pragma unroll
      for (int rr = 0; rr < 4; rr++){
        const int l = i*16 + lgrp*4 + rr;
        orow[(size_t)l * DIMM + j*16 + lrow] = __float2bfloat16(o[i][j][rr]);
      }
}

// ---------------- host launch --------------------------------------------------------
extern "C" void kernel_launch(void* const* d_in, const int* in_sizes, int n_in,
                              void* d_out, int out_size, void* d_ws, size_t ws_size,
                              hipStream_t stream) {
  const float* x     = (const float*)d_in[0];
  const float* ln1w  = (const float*)d_in[1];
  const float* ln1b  = (const float*)d_in[2];
  const float* ln2w  = (const float*)d_in[3];
  const float* ln2b  = (const float*)d_in[4];
  const float* qkvw  = (const float*)d_in[5];
  const float* qkvbi = (const float*)d_in[6];
  const float* projw = (const float*)d_in[7];
  const float* projb = (const float*)d_in[8];
  const float* rpb   = (const float*)d_in[9];
  const float* m1w   = (const float*)d_in[10];
  const float* m1b   = (const float*)d_in[11];
  const float* m2w   = (const float*)d_in[12];
  const float* m2b   = (const float*)d_in[13];

  bf16* wqkv  = (bf16*)d_ws;                 // 786432
  bf16* wproj = wqkv + 786432;               // 262144
  bf16* wm1   = wproj + 262144;              // 1048576
  bf16* wm2   = wm1 + 1048576;               // 1048576
  bf16* xw    = wm2 + 1048576;               // 8388608  (LN1 out / LN2 out / MLP2 p1)
  float* hbuf = (float*)(xw + 8388608);      // 8388608 f32 (MLP2 p0 region)
  bf16* qkvb  = (bf16*)(hbuf + 8388608);     // 3*8388608 (q,k,v)
  bf16* attno = qkvb + 3*(size_t)8388608;    // 8388608
  bf16* m1buf = qkvb;                        // reuse qkv+attno region (MLP1 out 33.5M)
  bf16* h2    = xw;                          // reuse xw (LN2 out, token order)

  hipFuncSetAttribute((const void*)&gemm_sb<M_QKV, 512>,
                      hipFuncAttributeMaxDynamicSharedMemorySize, 65536);
  hipFuncSetAttribute((const void*)&gemm_sb<M_MLP1, 512>,
                      hipFuncAttributeMaxDynamicSharedMemorySize, 65536);
  hipFuncSetAttribute((const void*)&gemm_sb<M_PART, 1024, 2048>,
                      hipFuncAttributeMaxDynamicSharedMemorySize, 65536);
  hipFuncSetAttribute((const void*)&gemm_pl,
                      hipFuncAttributeMaxDynamicSharedMemorySize, 73728);

  convert_w<<<3072, 256, 0, stream>>>(qkvw, projw, m1w, m2w, wqkv);
  ln_kernel<true><<<4096, 256, 0, stream>>>(x, ln1w, ln1b, xw);
  { dim3 g(TOK/256, 1536/256);
    gemm_sb<M_QKV, 512><<<g, 512, 65536, stream>>>(xw, wqkv, qkvbi, qkvb, nullptr, nullptr); }
  attn_kernel<<<1024, 256, 0, stream>>>(qkvb, rpb, attno);
  // fused PROJ + residual + LN2: writes h2 directly (h never materialized)
  gemm_pl<<<TOK/64, 512, 73728, stream>>>(attno, wproj, projb, x, ln2w, ln2b, h2);
  { dim3 g(TOK/256, 2048/256);
    gemm_sb<M_MLP1, 512><<<g, 512, 65536, stream>>>(h2, wm1, m1b, m1buf, nullptr, nullptr); }
  // MLP2 split-K=2, bf16 partials: slab0 -> hbuf region, slab1 -> xw region
  { dim3 g(TOK/256, 512/256, 2);
    gemm_sb<M_PART, 1024, 2048><<<g, 512, 65536, stream>>>(m1buf, wm2, m2b, nullptr,
                                                           (float*)hbuf, (float*)xw); }
  mlp2_reduce<<<8388608/8/256, 256, 0, stream>>>((const bf16*)hbuf, (const bf16*)xw,
                                                 (float*)d_out, m2b);
}

// Round 17
// 210.132 us; speedup vs baseline: 7.1900x; 7.1900x over previous
//
#include <hip/hip_runtime.h>
#include <hip/hip_bf16.h>
#include <stdint.h>

// Problem constants (all static per reference)
#define TOK   16384
#define DIMM  512
#define NHEAD 16
#define HDIM  32
#define HID   2048
#define NWIN  256
#define WLEN  64
#define EPSV  1e-5f
#define SCL   0.17677669529663687f   // 32^-0.5

typedef __hip_bfloat16 bf16;
typedef __attribute__((ext_vector_type(8))) __bf16 bf16x8;
typedef __attribute__((ext_vector_type(4))) float f32x4;

// window-order row r (win*64 + l, shifted coords) -> original token row
__device__ __forceinline__ int remap_row(int r){
  int win = r >> 6, l = r & 63;
  int gh = ((win >> 4) << 3) + (l >> 3);
  int gw = ((win & 15) << 3) + (l & 7);
  int oh = (gh + 4) & 127, ow = (gw + 4) & 127;
  return (oh << 7) + ow;
}

// Swin shift-mask region id (slices: [0,120) [120,124) [124,128) on each axis)
__device__ __forceinline__ int region_of(int win, int l){
  int gh = ((win >> 4) << 3) + (l >> 3);
  int gw = ((win & 15) << 3) + (l & 7);
  int rh = (gh < 120) ? 0 : ((gh < 124) ? 1 : 2);
  int rw = (gw < 120) ? 0 : ((gw < 124) ? 1 : 2);
  return rh * 3 + rw;
}

__device__ __forceinline__ void gl_lds16(const bf16* g, bf16* l){
  __builtin_amdgcn_global_load_lds((const __attribute__((address_space(1))) void*)g,
                                   (__attribute__((address_space(3))) void*)l, 16, 0, 0);
}

// ---------------- weight fp32 -> bf16 convert (4 ranges, contiguous dst) -------------
__global__ __launch_bounds__(256) void convert_w(const float* __restrict__ a,
                                                 const float* __restrict__ b,
                                                 const float* __restrict__ c,
                                                 const float* __restrict__ d,
                                                 bf16* __restrict__ dst){
  int e = (blockIdx.x * 256 + threadIdx.x) * 4;
  float4 v;
  if (e < 786432)        v = *(const float4*)(a + e);
  else if (e < 1048576)  v = *(const float4*)(b + (e - 786432));
  else if (e < 2097152)  v = *(const float4*)(c + (e - 1048576));
  else                   v = *(const float4*)(d + (e - 2097152));
  union { bf16 h[4]; int2 q; } u;
  u.h[0] = __float2bfloat16(v.x); u.h[1] = __float2bfloat16(v.y);
  u.h[2] = __float2bfloat16(v.z); u.h[3] = __float2bfloat16(v.w);
  *(int2*)(dst + e) = u.q;
}

// ---------------- LayerNorm (one wave per row) + shift+window remap (LN1 only) -------
template<bool REMAP>
__global__ __launch_bounds__(256) void ln_kernel(const float* __restrict__ in,
    const float* __restrict__ w, const float* __restrict__ b, bf16* __restrict__ outp)
{
  const int wave = threadIdx.x >> 6, lane = threadIdx.x & 63;
  const int r = blockIdx.x * 4 + wave;
  const int src = REMAP ? remap_row(r) : r;
  const float4* row = (const float4*)(in + (size_t)src * DIMM);
  float4 v0 = row[lane*2], v1 = row[lane*2 + 1];
  float sm = v0.x+v0.y+v0.z+v0.w + v1.x+v1.y+v1.z+v1.w;
  float sq = v0.x*v0.x+v0.y*v0.y+v0.z*v0.z+v0.w*v0.w
           + v1.x*v1.x+v1.y*v1.y+v1.z*v1.z+v1.w*v1.w;
  #pragma unroll
  for (int off = 1; off < 64; off <<= 1){
    sm += __shfl_xor(sm, off);
    sq += __shfl_xor(sq, off);
  }
  const float mean = sm * (1.f/512.f);
  const float rstd = rsqrtf(sq*(1.f/512.f) - mean*mean + EPSV);
  const float4* wp = (const float4*)w; const float4* bp = (const float4*)b;
  float4 w0 = wp[lane*2], w1 = wp[lane*2+1], b0 = bp[lane*2], b1 = bp[lane*2+1];
  union { bf16 h[8]; int4 q; } u;
  u.h[0] = __float2bfloat16((v0.x-mean)*rstd*w0.x + b0.x);
  u.h[1] = __float2bfloat16((v0.y-mean)*rstd*w0.y + b0.y);
  u.h[2] = __float2bfloat16((v0.z-mean)*rstd*w0.z + b0.z);
  u.h[3] = __float2bfloat16((v0.w-mean)*rstd*w0.w + b0.w);
  u.h[4] = __float2bfloat16((v1.x-mean)*rstd*w1.x + b1.x);
  u.h[5] = __float2bfloat16((v1.y-mean)*rstd*w1.y + b1.y);
  u.h[6] = __float2bfloat16((v1.z-mean)*rstd*w1.z + b1.z);
  u.h[7] = __float2bfloat16((v1.w-mean)*rstd*w1.w + b1.w);
  *(int4*)(outp + (size_t)r*DIMM + lane*8) = u.q;
}

#define M_QKV  0
#define M_MLP1 2
#define M_PART 4

// ---------------- 256x256 GEMM: counted-lgkm + cross-tile fragment prefetch ----------
// (R13, best verified across 4 clean runs). Quad order (A0B0),(A1B0),(A0B1),
// (A1B1): A0 dies ph3, B0 ph2 -> ph4 re-reads NEXT tile's A0,B0 into the SAME
// registers (register-neutral). Prefetch sits after ph4's vmcnt+barrier =>
// all waves' K(t+1) stages retired (RAW-safe).
// DS ledger per tile (in-order; groups pinned by sched_barrier):
//   entry: 12 outstanding (A0,B0 prefetched at ph4(t-1))
//   ph1: issue A1(8)->20; stage K(t+1).A1->sx; LGKM(8) retires A0,B0; quad(A0B0)
//   ph2: issue B1(4)->12; LGKM(4) retires A1;                        quad(A1B0)
//   ph3: stage K(t+2).B0->s; LGKM(0) retires B1;                     quad(A0B1)
//   ph4: stage K(t+2).{A0,B1}->s; vmcnt(6|0); SBAR; prefetch A0,B0(sx); quad(A1B1)
// WAR: A0(s) reads retired ph1 -> stage ph4 OK; B0(s) retired ph1 -> stage ph3
// OK; B1(s) retired ph3 -> stage ph4 OK; A1(sx) retired ph2(t-1) -> stage ph1
// OK. VM ledger: vmcnt(6) steady, 0 at NT-2.
// Design-space boundary notes (measured, do not retry):
//  - NO XCD swizzle (R11: FETCH 24.8->67.8MB).
//  - NO 4-wave/BK=32 blocks (R14: 56->72us, barrier frequency).
//  - NO launch_bounds min-waves>1 (R16: 128-reg acc spills to scratch, 2.4GB).
//  - NO 32x32 MFMA 4-wave variant (R10: 1 wave/SIMD, no TLP).
template<int KSTR>
__device__ __forceinline__ void stage_ht(const bf16* __restrict__ P,
                                         int grow0, bf16* lbase, int tid, int kt){
  const int r = tid >> 3;
  const int c = ((tid & 7) ^ (r & 7)) * 8;      // pre-swizzled source column
  const bf16* g = P + (size_t)(grow0 + r) * KSTR + kt * 64 + c;
  bf16* l = lbase + r * 64 + (tid & 7) * 8;     // linear dest (wave base + lane*16B)
  gl_lds16(g, l);
  gl_lds16(g + (size_t)64 * KSTR, l + 4096);
}

template<int MODE, int KEXT, int KSTR = KEXT>
__global__ __launch_bounds__(512, 1) void gemm8_bt(const bf16* __restrict__ A,
    const bf16* __restrict__ Wt, const float* __restrict__ bias,
    bf16* __restrict__ out_b, float* __restrict__ out_f, float* __restrict__ out_f2)
{
  constexpr int NT = KEXT / 64;
  extern __shared__ bf16 lds[];
  bf16* As = lds;            // [2][256][64] swizzled
  bf16* Bs = lds + 32768;    // [2][256][64] swizzled
  const int tid = threadIdx.x;
  const int ln = tid & 63, wv = tid >> 6;
  const int lrow = ln & 15, lgrp = ln >> 4;
  const int swz = lrow & 7;
  const int wm = wv >> 2, wn = wv & 3;
  const int m0 = blockIdx.x * 256, n0 = blockIdx.y * 256;

  if constexpr (MODE == M_PART){          // split-K slab select
    A  += blockIdx.z * 1024;
    Wt += blockIdx.z * 1024;
  }

  f32x4 acc[8][4] = {};
  bf16x8 aA0[4][2], aA1[4][2], bB0[2][2], bB1[2][2];

  #define LDAS(DST, MH, SL) { _Pragma("unroll") for (int mf = 0; mf < 4; mf++) \
    _Pragma("unroll") for (int ks = 0; ks < 2; ks++) \
      DST[mf][ks] = *(const bf16x8*)(As + (SL)*16384 + (wm*128 + (MH)*64 + mf*16 + lrow)*64 + ((ks*4 + lgrp) ^ swz)*8); }
  #define LDBS(DST, NH, SL) { _Pragma("unroll") for (int nf = 0; nf < 2; nf++) \
    _Pragma("unroll") for (int ks = 0; ks < 2; ks++) \
      DST[nf][ks] = *(const bf16x8*)(Bs + (SL)*16384 + (wn*64 + (NH)*32 + nf*16 + lrow)*64 + ((ks*4 + lgrp) ^ swz)*8); }
  #define QUAD(AR, BR, IM0, JN0) { _Pragma("unroll") for (int ks = 0; ks < 2; ks++) \
    _Pragma("unroll") for (int mf = 0; mf < 4; mf++) \
      _Pragma("unroll") for (int nf = 0; nf < 2; nf++) \
        acc[(IM0)+mf][(JN0)+nf] = __builtin_amdgcn_mfma_f32_16x16x32_bf16(AR[mf][ks], BR[nf][ks], acc[(IM0)+mf][(JN0)+nf], 0, 0, 0); }
  #define SBAR() { __builtin_amdgcn_sched_barrier(0); __builtin_amdgcn_s_barrier(); __builtin_amdgcn_sched_barrier(0); }
  #define LGKM(N) { asm volatile("s_waitcnt lgkmcnt(" #N ")" ::: "memory"); __builtin_amdgcn_sched_barrier(0); }

  // ---- prologue (order-insensitive): K0 all 4 half-tiles, drain, barrier
  stage_ht<KSTR>(A,  m0,       As,        tid, 0);
  stage_ht<KSTR>(Wt, n0,       Bs,        tid, 0);
  stage_ht<KSTR>(Wt, n0 + 128, Bs + 8192, tid, 0);
  stage_ht<KSTR>(A,  m0 + 128, As + 8192, tid, 0);
  asm volatile("s_waitcnt vmcnt(0)" ::: "memory");
  SBAR();
  // prefetch tile-0 fragment reads (slot 0); then K1 stage group in flight
  LDAS(aA0, 0, 0); LDBS(bB0, 0, 0);
  __builtin_amdgcn_sched_barrier(0);
  stage_ht<KSTR>(Wt, n0,       Bs + 16384,        tid, 1);
  stage_ht<KSTR>(A,  m0,       As + 16384,        tid, 1);
  stage_ht<KSTR>(Wt, n0 + 128, Bs + 16384 + 8192, tid, 1);

  for (int t = 0; t < NT; ++t){
    const int s = t & 1;
    const int sx = s ^ 1;
    // ---- phase 1: issue A1(8); stage K(t+1).A1 -> sx; wait prefetched A0,B0
    LDAS(aA1, 1, s);
    if (t + 1 < NT) stage_ht<KSTR>(A, m0 + 128, As + sx*16384 + 8192, tid, t + 1);
    LGKM(8);
    __builtin_amdgcn_s_setprio(1); QUAD(aA0, bB0, 0, 0); __builtin_amdgcn_s_setprio(0);
    SBAR();
    // ---- phase 2: issue B1(4); wait A1; quad(A1xB0)  [B0 dead after this]
    LDBS(bB1, 1, s);
    LGKM(4);
    __builtin_amdgcn_s_setprio(1); QUAD(aA1, bB0, 4, 0); __builtin_amdgcn_s_setprio(0);
    SBAR();
    // ---- phase 3: stage K(t+2).B0 -> s; wait B1; quad(A0xB1)  [A0 dead after this]
    if (t + 2 < NT) stage_ht<KSTR>(Wt, n0, Bs + s*16384, tid, t + 2);
    LGKM(0);
    __builtin_amdgcn_s_setprio(1); QUAD(aA0, bB1, 0, 2); __builtin_amdgcn_s_setprio(0);
    SBAR();
    // ---- phase 4: stage K(t+2).{A0,B1} -> s; vmcnt; bar; PREFETCH next A0,B0; quad
    if (t + 2 < NT){
      stage_ht<KSTR>(A,  m0,       As + s*16384,        tid, t + 2);
      stage_ht<KSTR>(Wt, n0 + 128, Bs + s*16384 + 8192, tid, t + 2);
    }
    if (t == NT - 2)      { asm volatile("s_waitcnt vmcnt(0)" ::: "memory"); }
    else if (t < NT - 2)  { asm volatile("s_waitcnt vmcnt(6)" ::: "memory"); }
    SBAR();
    if (t + 1 < NT){
      LDAS(aA0, 0, sx); LDBS(bB0, 0, sx);    // same regs: old A0/B0 are dead
      __builtin_amdgcn_sched_barrier(0);
    }
    __builtin_amdgcn_s_setprio(1); QUAD(aA1, bB1, 4, 2); __builtin_amdgcn_s_setprio(0);
  }
  #undef LDAS
  #undef LDBS
  #undef QUAD
  #undef SBAR
  #undef LGKM

  // ---- epilogue
  bf16* pdstb = nullptr;
  if constexpr (MODE == M_PART)
    pdstb = blockIdx.z ? (bf16*)out_f2 : (bf16*)out_f;   // bf16 split-K partials
  #pragma unroll
  for (int im = 0; im < 8; im++){
    #pragma unroll
    for (int jn = 0; jn < 4; jn++){
      const int col = n0 + wn*64 + (jn >> 1)*32 + (jn & 1)*16 + lrow;
      const int row_b = m0 + wm*128 + (im >> 2)*64 + (im & 3)*16 + lgrp*4;
      const float bv = (MODE == M_PART) ? 0.f : bias[col];
      #pragma unroll
      for (int rr = 0; rr < 4; rr++){
        const int row = row_b + rr;
        float v = acc[im][jn][rr] + bv;
        if constexpr (MODE == M_QKV){
          const int t = col >> 9, rem = col & 511;
          const int head = rem >> 5, hd = rem & 31;
          const int win = row >> 6, l = row & 63;
          out_b[(size_t)t * (TOK*DIMM) + ((size_t)(win*NHEAD + head)*WLEN + l)*HDIM + hd]
              = __float2bfloat16(v);
        } else if constexpr (MODE == M_MLP1){
          const float u = 1.5957691216057308f * (v + 0.044715f*v*v*v);
          const float g = v * (1.0f / (1.0f + __expf(-u)));
          out_b[(size_t)row*HID + col] = __float2bfloat16(g);
        } else if constexpr (MODE == M_PART){
          pdstb[(size_t)row*DIMM + col] = __float2bfloat16(v);  // raw partial
        }
      }
    }
  }
}

// -------- fused PROJ + residual + LayerNorm2: h never materialized (R12, proven) -----
__global__ __launch_bounds__(512, 1) void gemm_pl(const bf16* __restrict__ Ain,
    const bf16* __restrict__ Wt, const float* __restrict__ pb,
    const float* __restrict__ x, const float* __restrict__ w2,
    const float* __restrict__ b2, bf16* __restrict__ h2)
{
  extern __shared__ bf16 lds[];
  bf16* As = lds;            // [2][64][32]  = 8 KB
  bf16* Bs = lds + 4096;     // [2][512][32] = 64 KB
  const int tid = threadIdx.x;
  const int ln = tid & 63, wv = tid >> 6;
  const int lrow = ln & 15, lgrp = ln >> 4;
  const int m0 = blockIdx.x * 64;

  f32x4 acc[4][4] = {};

  const int brow = tid >> 2;                                // 0..127
  const int bchunk = ((tid & 3) ^ ((tid >> 3) & 3)) * 8;    // swizzled src col
  const int dst = brow * 32 + (tid & 3) * 8;                // linear dest

  #define STAGE(kt, sl) { \
    _Pragma("unroll") for (int i = 0; i < 4; i++) \
      gl_lds16(Wt + (size_t)(i*128 + brow)*DIMM + (kt)*32 + bchunk, Bs + (sl)*16384 + i*4096 + dst); \
    if (tid < 256) gl_lds16(Ain + (size_t)(m0 + brow)*DIMM + (kt)*32 + bchunk, As + (sl)*2048 + dst); \
  }

  const int rswz = (lgrp ^ ((lrow >> 1) & 3)) * 8;

  STAGE(0, 0);
  __syncthreads();
  for (int kt = 0; kt < 16; ++kt){
    const int s = kt & 1;
    if (kt + 1 < 16) STAGE(kt + 1, s ^ 1);
    bf16x8 a[4], b[4];
    #pragma unroll
    for (int mf = 0; mf < 4; mf++)
      a[mf] = *(const bf16x8*)(As + s*2048 + (mf*16 + lrow)*32 + rswz);
    #pragma unroll
    for (int nf = 0; nf < 4; nf++)
      b[nf] = *(const bf16x8*)(Bs + s*16384 + (wv*64 + nf*16 + lrow)*32 + rswz);
    #pragma unroll
    for (int mf = 0; mf < 4; mf++)
      #pragma unroll
      for (int nf = 0; nf < 4; nf++)
        acc[mf][nf] = __builtin_amdgcn_mfma_f32_16x16x32_bf16(a[mf], b[nf], acc[mf][nf], 0, 0, 0);
    __syncthreads();
  }
  #undef STAGE

  // ---- epilogue: residual + row stats (As/Bs dead past final barrier)
  float* red = (float*)lds;   // [8][64][2] f32 = 4 KB
  #pragma unroll
  for (int mf = 0; mf < 4; mf++){
    #pragma unroll
    for (int rr = 0; rr < 4; rr++){
      const int r = mf*16 + lgrp*4 + rr;
      const int o = remap_row(m0 + r);
      float sm = 0.f, sq = 0.f;
      #pragma unroll
      for (int nf = 0; nf < 4; nf++){
        const int col = wv*64 + nf*16 + lrow;
        float v = acc[mf][nf][rr] + pb[col] + x[(size_t)o*DIMM + col];
        acc[mf][nf][rr] = v;
        sm += v; sq += v*v;
      }
      sm += __shfl_xor(sm, 1); sq += __shfl_xor(sq, 1);
      sm += __shfl_xor(sm, 2); sq += __shfl_xor(sq, 2);
      sm += __shfl_xor(sm, 4); sq += __shfl_xor(sq, 4);
      sm += __shfl_xor(sm, 8); sq += __shfl_xor(sq, 8);
      if (lrow == 0){ red[(wv*64 + r)*2] = sm; red[(wv*64 + r)*2 + 1] = sq; }
    }
  }
  __syncthreads();
  if (tid < 64){
    float sm = 0.f, sq = 0.f;
    #pragma unroll
    for (int w = 0; w < 8; w++){ sm += red[(w*64 + tid)*2]; sq += red[(w*64 + tid)*2 + 1]; }
    const float mean = sm * (1.f/512.f);
    const float var  = sq * (1.f/512.f) - mean*mean;
    red[tid*2]     = mean;
    red[tid*2 + 1] = rsqrtf(var + EPSV);
  }
  __syncthreads();
  #pragma unroll
  for (int mf = 0; mf < 4; mf++){
    #pragma unroll
    for (int rr = 0; rr < 4; rr++){
      const int r = mf*16 + lgrp*4 + rr;
      const int o = remap_row(m0 + r);
      const float mean = red[r*2], rstd = red[r*2 + 1];
      #pragma unroll
      for (int nf = 0; nf < 4; nf++){
        const int col = wv*64 + nf*16 + lrow;
        const float g = (acc[mf][nf][rr] - mean) * rstd * w2[col] + b2[col];
        h2[(size_t)o*DIMM + col] = __float2bfloat16(g);
      }
    }
  }
}

// ---------------- MLP2 split-K reduce: d_out = 2*(p0 + p1 + bias), 8 elems/thread ----
__global__ __launch_bounds__(256) void mlp2_reduce(const bf16* __restrict__ p0,
    const bf16* __restrict__ p1, float* __restrict__ dout, const float* __restrict__ bias){
  const size_t i = (size_t)(blockIdx.x * 256 + threadIdx.x) * 8;
  int4 a = *(const int4*)(p0 + i);
  int4 b = *(const int4*)(p1 + i);
  const int cb = (int)(i & 511);
  const float4 bv0 = *(const float4*)(bias + cb);
  const float4 bv1 = *(const float4*)(bias + cb + 4);
  const bf16* ah = (const bf16*)&a;
  const bf16* bh = (const bf16*)&b;
  float4 r0, r1;
  r0.x = 2.f*(__bfloat162float(ah[0]) + __bfloat162float(bh[0]) + bv0.x);
  r0.y = 2.f*(__bfloat162float(ah[1]) + __bfloat162float(bh[1]) + bv0.y);
  r0.z = 2.f*(__bfloat162float(ah[2]) + __bfloat162float(bh[2]) + bv0.z);
  r0.w = 2.f*(__bfloat162float(ah[3]) + __bfloat162float(bh[3]) + bv0.w);
  r1.x = 2.f*(__bfloat162float(ah[4]) + __bfloat162float(bh[4]) + bv1.x);
  r1.y = 2.f*(__bfloat162float(ah[5]) + __bfloat162float(bh[5]) + bv1.y);
  r1.z = 2.f*(__bfloat162float(ah[6]) + __bfloat162float(bh[6]) + bv1.z);
  r1.w = 2.f*(__bfloat162float(ah[7]) + __bfloat162float(bh[7]) + bv1.w);
  *(float4*)(dout + i)     = r0;
  *(float4*)(dout + i + 4) = r1;
}

// ---------------- windowed attention: one wave per (window, head) --------------------
__global__ __launch_bounds__(256) void attn_kernel(const bf16* __restrict__ qkv,
    const float* __restrict__ rpb, bf16* __restrict__ outp)
{
  __shared__ bf16 Pl[4][64][72];
  const int wave = threadIdx.x >> 6, lane = threadIdx.x & 63;
  const int lrow = lane & 15, lgrp = lane >> 4;
  const int wh = blockIdx.x * 4 + wave;
  const int win = wh >> 4, head = wh & 15;
  const bf16* qb = qkv + (size_t)wh * (WLEN*HDIM);
  const bf16* kb = qb + (size_t)TOK * DIMM;
  const bf16* vb = kb + (size_t)TOK * DIMM;

  bf16x8 aq[4], ak[4];
  #pragma unroll
  for (int i = 0; i < 4; i++){
    aq[i] = *(const bf16x8*)(qb + (i*16 + lrow)*HDIM + lgrp*8);
    ak[i] = *(const bf16x8*)(kb + (i*16 + lrow)*HDIM + lgrp*8);
  }
  f32x4 s[4][4] = {};
  #pragma unroll
  for (int i = 0; i < 4; i++)
    #pragma unroll
    for (int j = 0; j < 4; j++)
      s[i][j] = __builtin_amdgcn_mfma_f32_16x16x32_bf16(aq[i], ak[j], s[i][j], 0, 0, 0);

  #pragma unroll
  for (int i = 0; i < 4; i++){
    #pragma unroll
    for (int rr = 0; rr < 4; rr++){
      const int srow = i*16 + lgrp*4 + rr;
      const int rq = region_of(win, srow);
      float vals[4]; float mx = -1e30f;
      #pragma unroll
      for (int j = 0; j < 4; j++){
        const int scol = j*16 + lrow;
        const int idx = ((srow>>3) - (scol>>3) + 7)*15 + ((srow&7) - (scol&7) + 7);
        float v = s[i][j][rr]*SCL + rpb[idx*NHEAD + head];
        if (region_of(win, scol) != rq) v -= 100.f;
        vals[j] = v; mx = fmaxf(mx, v);
      }
      mx = fmaxf(mx, __shfl_xor(mx, 1));
      mx = fmaxf(mx, __shfl_xor(mx, 2));
      mx = fmaxf(mx, __shfl_xor(mx, 4));
      mx = fmaxf(mx, __shfl_xor(mx, 8));
      float sum = 0.f;
      #pragma unroll
      for (int j = 0; j < 4; j++){ vals[j] = __expf(vals[j] - mx); sum += vals[j]; }
      sum += __shfl_xor(sum, 1); sum += __shfl_xor(sum, 2);
      sum += __shfl_xor(sum, 4); sum += __shfl_xor(sum, 8);
      const float rs = 1.f / sum;
      #pragma unroll
      for (int j = 0; j < 4; j++)
        Pl[wave][srow][j*16 + lrow] = __float2bfloat16(vals[j] * rs);
    }
  }

  f32x4 o[4][2] = {};
  const __bf16* vraw = (const __bf16*)vb;
  #pragma unroll
  for (int st = 0; st < 2; st++){
    bf16x8 pa[4];
    #pragma unroll
    for (int i = 0; i < 4; i++)
      pa[i] = *(const bf16x8*)(&Pl[wave][i*16 + lrow][st*32 + lgrp*8]);
    bf16x8 bv[2];
    #pragma unroll
    for (int j = 0; j < 2; j++){
      #pragma unroll
      for (int jj = 0; jj < 8; jj++)
        bv[j][jj] = vraw[(size_t)(st*32 + lgrp*8 + jj)*HDIM + j*16 + lrow];
    }
    #pragma unroll
    for (int i = 0; i < 4; i++)
      #pragma unroll
      for (int j = 0; j < 2; j++)
        o[i][j] = __builtin_amdgcn_mfma_f32_16x16x32_bf16(pa[i], bv[j], o[i][j], 0, 0, 0);
  }
  bf16* orow = outp + (size_t)win * WLEN * DIMM + head * HDIM;
  #pragma unroll
  for (int i = 0; i < 4; i++)
    #pragma unroll
    for (int j = 0; j < 2; j++)
      #pragma unroll
      for (int rr = 0; rr < 4; rr++){
        const int l = i*16 + lgrp*4 + rr;
        orow[(size_t)l * DIMM + j*16 + lrow] = __float2bfloat16(o[i][j][rr]);
      }
}

// ---------------- host launch --------------------------------------------------------
extern "C" void kernel_launch(void* const* d_in, const int* in_sizes, int n_in,
                              void* d_out, int out_size, void* d_ws, size_t ws_size,
                              hipStream_t stream) {
  const float* x     = (const float*)d_in[0];
  const float* ln1w  = (const float*)d_in[1];
  const float* ln1b  = (const float*)d_in[2];
  const float* ln2w  = (const float*)d_in[3];
  const float* ln2b  = (const float*)d_in[4];
  const float* qkvw  = (const float*)d_in[5];
  const float* qkvbi = (const float*)d_in[6];
  const float* projw = (const float*)d_in[7];
  const float* projb = (const float*)d_in[8];
  const float* rpb   = (const float*)d_in[9];
  const float* m1w   = (const float*)d_in[10];
  const float* m1b   = (const float*)d_in[11];
  const float* m2w   = (const float*)d_in[12];
  const float* m2b   = (const float*)d_in[13];

  bf16* wqkv  = (bf16*)d_ws;                 // 786432
  bf16* wproj = wqkv + 786432;               // 262144
  bf16* wm1   = wproj + 262144;              // 1048576
  bf16* wm2   = wm1 + 1048576;               // 1048576
  bf16* xw    = wm2 + 1048576;               // 8388608  (LN1 out / LN2 out / MLP2 p1)
  float* hbuf = (float*)(xw + 8388608);      // 8388608 f32 (MLP2 p0 region)
  bf16* qkvb  = (bf16*)(hbuf + 8388608);     // 3*8388608 (q,k,v)
  bf16* attno = qkvb + 3*(size_t)8388608;    // 8388608
  bf16* m1buf = qkvb;                        // reuse qkv+attno region (MLP1 out 33.5M)
  bf16* h2    = xw;                          // reuse xw (LN2 out, token order)

  hipFuncSetAttribute((const void*)&gemm8_bt<M_QKV, 512>,
                      hipFuncAttributeMaxDynamicSharedMemorySize, 131072);
  hipFuncSetAttribute((const void*)&gemm8_bt<M_MLP1, 512>,
                      hipFuncAttributeMaxDynamicSharedMemorySize, 131072);
  hipFuncSetAttribute((const void*)&gemm8_bt<M_PART, 1024, 2048>,
                      hipFuncAttributeMaxDynamicSharedMemorySize, 131072);
  hipFuncSetAttribute((const void*)&gemm_pl,
                      hipFuncAttributeMaxDynamicSharedMemorySize, 73728);

  convert_w<<<3072, 256, 0, stream>>>(qkvw, projw, m1w, m2w, wqkv);
  ln_kernel<true><<<4096, 256, 0, stream>>>(x, ln1w, ln1b, xw);
  { dim3 g(TOK/256, 1536/256);
    gemm8_bt<M_QKV, 512><<<g, 512, 131072, stream>>>(xw, wqkv, qkvbi, qkvb, nullptr, nullptr); }
  attn_kernel<<<1024, 256, 0, stream>>>(qkvb, rpb, attno);
  // fused PROJ + residual + LN2: writes h2 directly (h never materialized)
  gemm_pl<<<TOK/64, 512, 73728, stream>>>(attno, wproj, projb, x, ln2w, ln2b, h2);
  { dim3 g(TOK/256, 2048/256);
    gemm8_bt<M_MLP1, 512><<<g, 512, 131072, stream>>>(h2, wm1, m1b, m1buf, nullptr, nullptr); }
  // MLP2 split-K=2, bf16 partials: slab0 -> hbuf region, slab1 -> xw region
  { dim3 g(TOK/256, 512/256, 2);
    gemm8_bt<M_PART, 1024, 2048><<<g, 512, 131072, stream>>>(m1buf, wm2, m2b, nullptr,
                                                             (float*)hbuf, (float*)xw); }
  mlp2_reduce<<<8388608/8/256, 256, 0, stream>>>((const bf16*)hbuf, (const bf16*)xw,
                                                 (float*)d_out, m2b);
}